// Round 1
// baseline (126.981 us; speedup 1.0000x reference)
//
#include <hip/hip_runtime.h>
#include <math.h>

#define CELLN 14
#define NCELLS 196      // 14*14
#define NCLS 80
#define NCH 95          // 80 + 5*3

__global__ __launch_bounds__(256) void yolo_loss_kernel(
    const float* __restrict__ predicts,
    const float* __restrict__ labels,
    const int* __restrict__ objects_num,
    float* __restrict__ out,
    int M, float invB)
{
    __shared__ float s_pP[NCELLS * NCLS];   // 62720 B: class logits per cell
    __shared__ float s_classSS[NCELLS];     // per-cell sum of squares over 80 classes
    __shared__ float s_red[8];

    const int img  = blockIdx.x;
    const int tid  = threadIdx.x;
    const int lane = tid & 63;
    const int wid  = tid >> 6;
    const int sub  = lane & 15;   // position within 16-lane cluster
    const int c4   = lane >> 4;   // cluster id within wave (0..3)

    const float* gpred = predicts + (size_t)img * (NCELLS * NCH);

    // ---------- Phase 1: stream the image, build classSS + p_C sumsq ----------
    float pc2 = 0.0f;
    for (int c0 = 0; c0 < NCELLS; c0 += 16) {
        int cell = c0 + (wid << 2) + c4;       // 16 cells per block-iteration
        float cls_acc = 0.0f, pc_acc = 0.0f;
        if (cell < NCELLS) {
            const float* cp = gpred + cell * NCH;
            #pragma unroll
            for (int j = 0; j < 5; ++j) {      // ch = sub + 16j in [0,80)
                int ch = sub + 16 * j;
                float v = cp[ch];
                cls_acc += v * v;
                s_pP[cell * NCLS + ch] = v;    // 2-way bank aliasing only (free)
            }
            if (sub < 3) {                     // confidence channels 80..82
                float v = cp[NCLS + sub];
                pc_acc = v * v;
            }
        }
        #pragma unroll
        for (int off = 8; off; off >>= 1) {    // butterfly within the 16-lane cluster
            cls_acc += __shfl_xor(cls_acc, off, 16);
            pc_acc  += __shfl_xor(pc_acc,  off, 16);
        }
        if (sub == 0 && cell < NCELLS) {
            s_classSS[cell] = cls_acc;
            pc2 += pc_acc;
        }
    }

    // ---------- Phase 2: block-reduce total p_C^2 ----------
    #pragma unroll
    for (int off = 32; off; off >>= 1) pc2 += __shfl_down(pc2, off);
    if (lane == 0) s_red[wid] = pc2;
    __syncthreads();                            // also publishes s_pP / s_classSS
    const float S_pC2 = s_red[0] + s_red[1] + s_red[2] + s_red[3];

    // ---------- Phase 3: one 8-lane group per object ----------
    float acc = 0.0f;
    const int g = tid >> 3;
    const int r = tid & 7;
    const int n = objects_num[img];
    if (g < n) {
        const float* lab = labels + ((size_t)img * M + g) * 5;
        const float x = lab[0], y = lab[1], w = lab[2], h = lab[3];
        const int cls = (int)lab[4];
        const float inv32 = 1.0f / 32.0f;

        int min_x = max(0, (int)floorf((x - w * 0.5f) * inv32));
        int max_x = min(CELLN, (int)ceilf((x + w * 0.5f) * inv32));
        int min_y = max(0, (int)floorf((y - h * 0.5f) * inv32));
        int max_y = min(CELLN, (int)ceilf((y + h * 0.5f) * inv32));
        int nx = max_x - min_x;
        int ncell = nx * (max_y - min_y);

        // class loss: sum_c (p - onehot)^2 = classSS - 2*p[cls] + 1, over mask cells
        float csum = 0.0f;
        for (int p = r; p < ncell; p += 8) {
            int gy = min_y + p / nx;
            int gx = min_x + p % nx;
            int cell = gy * CELLN + gx;
            csum += s_classSS[cell] - 2.0f * s_pP[cell * NCLS + cls] + 1.0f;
        }
        acc = 0.5f * csum;

        if (r == 0) {
            // center cell: ciou for 3 boxes, selection, object/noobject/coord
            int cx = (int)floorf(x * inv32);
            int cy = (int)floorf(y * inv32);
            int ccell = cy * CELLN + cx;
            const float* cp = gpred + ccell * NCH;
            float bx = (float)cx * 32.0f;
            float by = (float)cy * 32.0f;

            float pC[3], ciou[3], pxv[3], pyv[3], pwv[3], phv[3];
            #pragma unroll
            for (int b = 0; b < 3; ++b) {
                pC[b] = cp[NCLS + b];
                float px = cp[83 + 4*b] * 32.0f + bx;
                float py = cp[84 + 4*b] * 32.0f + by;
                float pw = cp[85 + 4*b] * 448.0f;
                float ph = cp[86 + 4*b] * 448.0f;
                pxv[b] = px; pyv[b] = py; pwv[b] = pw; phv[b] = ph;
                float iw = fminf(px + pw*0.5f, x + w*0.5f) - fmaxf(px - pw*0.5f, x - w*0.5f);
                float ih = fminf(py + ph*0.5f, y + h*0.5f) - fmaxf(py - ph*0.5f, y - h*0.5f);
                iw = fmaxf(iw, 0.0f); ih = fmaxf(ih, 0.0f);
                float inter = iw * ih;
                float uni = pw*ph + w*h - inter;
                float iou = inter / (uni + 1e-9f);
                float cd = (px - x)*(px - x) + (py - y)*(py - y);
                // NOTE: replicate reference's buggy enclose (uses cx/w as corners)
                float el = fminf(px, x), er = fmaxf(pw, w);
                float et = fminf(py, y), eb = fmaxf(ph, h);
                float ed = (er - el)*(er - el) + (eb - et)*(eb - et);
                float da = atanf(w / (h + 1e-9f)) - atanf(pw / (ph + 1e-9f));
                float v = 0.40528473456935108577f * da * da;   // 4/pi^2
                float alpha = v / (1.0f - iou + v + 1e-9f);
                ciou[b] = iou - cd / (ed + 1e-9f) - alpha * v;
            }
            float mx = fmaxf(ciou[0], fmaxf(ciou[1], ciou[2]));
            float sqw = sqrtf(fabsf(w)), sqh = sqrtf(fabsf(h));
            float sel_obj = 0.0f, sel_pc2 = 0.0f, coord = 0.0f;
            #pragma unroll
            for (int b = 0; b < 3; ++b) {
                if (ciou[b] >= mx) {           // I = (iou >= max) at center cell
                    float d = pC[b] - ciou[b]; // C = iou at center
                    sel_obj += d * d;
                    sel_pc2 += pC[b] * pC[b];
                    float dx = (pxv[b] - x) * inv32;
                    float dy = (pyv[b] - y) * inv32;
                    float psw = sqrtf(fminf(fmaxf(pwv[b], 0.0f), 448.0f));
                    float psh = sqrtf(fminf(fmaxf(phv[b], 0.0f), 448.0f));
                    float dw = psw - sqw, dh = psh - sqh;
                    coord += dx*dx + dy*dy + (dw*dw + dh*dh) * (1.0f/448.0f);
                }
            }
            // object(0.5) + noobject(0.25*(total - selected)) + coord(5*0.5)
            acc += 0.5f * sel_obj + 0.25f * (S_pC2 - sel_pc2) + 2.5f * coord;
        }
    }

    // ---------- final reduction: one atomic per block ----------
    #pragma unroll
    for (int off = 32; off; off >>= 1) acc += __shfl_down(acc, off);
    __syncthreads();           // everyone done reading s_red (S_pC2) before reuse
    if (lane == 0) s_red[wid] = acc;
    __syncthreads();
    if (tid == 0) {
        atomicAdd(out, (s_red[0] + s_red[1] + s_red[2] + s_red[3]) * invB);
    }
}

extern "C" void kernel_launch(void* const* d_in, const int* in_sizes, int n_in,
                              void* d_out, int out_size, void* d_ws, size_t ws_size,
                              hipStream_t stream) {
    const float* predicts = (const float*)d_in[0];
    const float* labels   = (const float*)d_in[1];
    const int*   objn     = (const int*)d_in[2];
    float* out = (float*)d_out;

    const int B = in_sizes[2];                 // objects_num has B entries
    const int M = in_sizes[1] / (B * 5);       // labels: (B, M, 5)

    hipMemsetAsync(out, 0, sizeof(float), stream);  // graph-capturable memset node
    yolo_loss_kernel<<<dim3(B), dim3(256), 0, stream>>>(
        predicts, labels, objn, out, M, 1.0f / (float)B);
}